// Round 1
// baseline (160203.357 us; speedup 1.0000x reference)
//
#include <hip/hip_runtime.h>
#include <hip/hip_bf16.h>

#define NCLS 3
#define NPTS 64
#define NEDGE 2016   // 64*63/2
#define MIN_SAMP 200

// Module-static device storage (avoids any dependence on ws_size).
__device__ int          g_counts[NCLS];
__device__ int          g_sel[NCLS][NPTS];
__device__ float        g_Dm[NCLS][NPTS * NPTS];
__device__ float        g_tp[NCLS];
__device__ unsigned int g_cols[NCLS][NEDGE][64];   // reduced columns, bitset 2016b = 64 x u32

__global__ void init_k() {
    if (threadIdx.x < NCLS) g_counts[threadIdx.x] = 0;
}

__global__ __launch_bounds__(256) void count_k(const int* __restrict__ labels, int N) {
    __shared__ int c3[NCLS];
    if (threadIdx.x < NCLS) c3[threadIdx.x] = 0;
    __syncthreads();
    for (int i = blockIdx.x * blockDim.x + threadIdx.x; i < N; i += gridDim.x * blockDim.x) {
        int c = labels[i];
        if ((unsigned)c < NCLS) atomicAdd(&c3[c], 1);
    }
    __syncthreads();
    if (threadIdx.x < NCLS) atomicAdd(&g_counts[threadIdx.x], c3[threadIdx.x]);
}

// Single thread: first 64 indices per class in ascending order (expected ~200 iters).
__global__ void select_k(const int* __restrict__ labels, int N) {
    int cnt[NCLS] = {0, 0, 0};
    for (int i = 0; i < N; ++i) {
        if (cnt[0] >= NPTS && cnt[1] >= NPTS && cnt[2] >= NPTS) break;
        int c = labels[i];
        if ((unsigned)c < NCLS && cnt[c] < NPTS) { g_sel[c][cnt[c]] = i; cnt[c]++; }
    }
}

__global__ __launch_bounds__(256) void dist_k(const float* __restrict__ feat) {
    int cls = blockIdx.x;
    if (g_counts[cls] < MIN_SAMP) return;
    for (int p = threadIdx.x; p < NPTS * NPTS; p += 256) {
        int i = p >> 6, j = p & 63;
        const float4* pi = (const float4*)(feat + (size_t)g_sel[cls][i] * 768);
        const float4* pj = (const float4*)(feat + (size_t)g_sel[cls][j] * 768);
        float sq = 0.f;
        #pragma unroll 4
        for (int d = 0; d < 192; ++d) {
            float4 va = pi[d], vb = pj[d];
            float dx = va.x - vb.x, dy = va.y - vb.y, dz = va.z - vb.z, dw = va.w - vb.w;
            sq = fmaf(dx, dx, sq); sq = fmaf(dy, dy, sq);
            sq = fmaf(dz, dz, sq); sq = fmaf(dw, dw, sq);
        }
        g_Dm[cls][p] = sqrtf(fmaxf(sq, 1e-12f));
    }
}

// One wave per class: edge ranking + boundary-matrix reduction (exact H1 persistence).
__global__ __launch_bounds__(64) void persist_k() {
    const int cls  = blockIdx.x;
    const int lane = threadIdx.x;
    if (g_counts[cls] < MIN_SAMP) return;

    __shared__ float         sDm[NPTS * NPTS];     // 16 KB
    __shared__ short         rank2d[NPTS * NPTS];  // 8 KB
    __shared__ unsigned char e2i[NEDGE], e2j[NEDGE];   // 4 KB
    __shared__ unsigned char se_i[NEDGE], se_j[NEDGE]; // 4 KB  (endpoints by rank)
    __shared__ float         ev[NEDGE];            // 8 KB  (value by rank)
    __shared__ unsigned char taken[NEDGE];         // 2 KB

    for (int p = lane; p < NPTS * NPTS; p += 64) sDm[p] = g_Dm[cls][p];
    if (lane < NPTS - 1) {
        int i = lane;
        int base = i * (2 * NPTS - 1 - i) / 2;     // i*(127-i)/2
        for (int j = i + 1; j < NPTS; ++j) {
            e2i[base + j - i - 1] = (unsigned char)i;
            e2j[base + j - i - 1] = (unsigned char)j;
        }
    }
    for (int p = lane; p < NEDGE; p += 64) taken[p] = 0;
    __syncthreads();

    // Rank every edge by (value, i, j) — O(E^2) comparisons, LDS-broadcast friendly.
    for (int e = lane; e < NEDGE; e += 64) {
        int i_ = e2i[e], j_ = e2j[e];
        float v = sDm[i_ * NPTS + j_];
        int rk = 0;
        for (int f = 0; f < NEDGE; ++f) {
            int fi = e2i[f], fj = e2j[f];
            float w = sDm[fi * NPTS + fj];
            bool less = (w < v) || (w == v && (fi < i_ || (fi == i_ && fj < j_)));
            rk += less ? 1 : 0;
        }
        se_i[rk] = (unsigned char)i_;
        se_j[rk] = (unsigned char)j_;
        ev[rk]   = v;
        rank2d[i_ * NPTS + j_] = (short)rk;
        rank2d[j_ * NPTS + i_] = (short)rk;
    }
    __syncthreads();

    double pers = 0.0;                      // uniform across lanes
    unsigned int* colbase = &g_cols[cls][0][0];

    // Triangles enumerated grouped by max-edge rank r (a legal filtration order).
    for (int r = 0; r < NEDGE; ++r) {
        const int i_ = se_i[r], j_ = se_j[r];
        int fa = -1, fb = -1;
        for (int k = 0; k < NPTS; ++k) {
            if (k == i_ || k == j_) continue;
            int a = rank2d[i_ * NPTS + k];
            int b = rank2d[j_ * NPTS + k];
            if (a >= r || b >= r) continue;            // not a maxr==r triangle
            unsigned int colw = 0;
            if (fa < 0) {
                // First triangle in group: apparent pair, claims pivot r; death-birth = 0.
                fa = a; fb = b;
                if ((a >> 5) == lane) colw ^= 1u << (a & 31);
                if ((b >> 5) == lane) colw ^= 1u << (b & 31);
                if ((r >> 5) == lane) colw ^= 1u << (r & 31);
                taken[r] = 1;
                colbase[(size_t)r * 64 + lane] = colw;
                continue;
            }
            // Start already reduced once: {a,b} XOR {fa,fb}  (skips the columns[r] load).
            if ((a  >> 5) == lane) colw ^= 1u << (a  & 31);
            if ((b  >> 5) == lane) colw ^= 1u << (b  & 31);
            if ((fa >> 5) == lane) colw ^= 1u << (fa & 31);
            if ((fb >> 5) == lane) colw ^= 1u << (fb & 31);
            while (true) {
                unsigned long long m = __ballot(colw != 0u);
                if (m == 0ull) break;                  // positive triangle
                int hl = 63 - __builtin_clzll(m);
                unsigned int hw = (unsigned int)__shfl((int)colw, hl, 64);
                int piv = (hl << 5) | (31 - __builtin_clz(hw));
                if (!taken[piv]) {
                    taken[piv] = 1;
                    colbase[(size_t)piv * 64 + lane] = colw;
                    pers += (double)ev[r] - (double)ev[piv];
                    break;
                }
                colw ^= colbase[(size_t)piv * 64 + lane];
            }
        }
    }
    if (lane == 0) g_tp[cls] = (float)pers;
}

__global__ void final_k(const float* __restrict__ tgt, float* __restrict__ out) {
    double total = 0.0;
    int valid = 0;
    for (int c = 0; c < NCLS; ++c) {
        if (g_counts[c] >= MIN_SAMP) {
            double tpt = 0.0;
            for (int p = 0; p < 100; ++p)
                tpt += (double)tgt[(c * 100 + p) * 2 + 1] - (double)tgt[(c * 100 + p) * 2 + 0];
            double d = (double)g_tp[c] - tpt;
            total += d * d;
            valid++;
        }
    }
    *out = valid ? (float)(total / valid) : 0.0f;
}

extern "C" void kernel_launch(void* const* d_in, const int* in_sizes, int n_in,
                              void* d_out, int out_size, void* d_ws, size_t ws_size,
                              hipStream_t stream) {
    const float* feat   = (const float*)d_in[0];
    const int*   labels = (const int*)d_in[1];
    const float* tgt    = (const float*)d_in[2];
    const int N = in_sizes[1];

    hipLaunchKernelGGL(init_k,   dim3(1),    dim3(64),  0, stream);
    hipLaunchKernelGGL(count_k,  dim3(256),  dim3(256), 0, stream, labels, N);
    hipLaunchKernelGGL(select_k, dim3(1),    dim3(1),   0, stream, labels, N);
    hipLaunchKernelGGL(dist_k,   dim3(NCLS), dim3(256), 0, stream, feat);
    hipLaunchKernelGGL(persist_k,dim3(NCLS), dim3(64),  0, stream);
    hipLaunchKernelGGL(final_k,  dim3(1),    dim3(1),   0, stream, tgt, (float*)d_out);
}